// Round 8
// baseline (132.558 us; speedup 1.0000x reference)
//
#include <hip/hip_runtime.h>

#define N_SAMP 16384
#define N_CENT 4096
#define DIM    128
#define LAMBD  1.0f
#define NSLOT  256

typedef _Float16 half8  __attribute__((ext_vector_type(8)));
typedef float    floatx4 __attribute__((ext_vector_type(4)));

struct Slot { float sum; unsigned int cnt; unsigned int pad[30]; };

// ---------------------------------------------------------------------------
// prep-lite: c2[c] = ||c||^2 and rowk[i] = lambd + c.(c - 2e) for c=center y_i,
// both computed from f16-ROUNDED values so the GEMM's diagonal entry
// v[i,y_i] = lambd exactly (up to fp32 ordering), enabling the
// exclusion-by-subtraction epilogue. Block 0 zeroes the slots.
// ---------------------------------------------------------------------------
__global__ __launch_bounds__(256) void prep_kernel(
    const float* __restrict__ E, const float* __restrict__ Cc,
    const int* __restrict__ tgt,
    float* __restrict__ c2, float* __restrict__ rowk,
    Slot* __restrict__ slots) {
  const int tid = threadIdx.x;
  if (blockIdx.x == 0) { slots[tid].sum = 0.f; slots[tid].cnt = 0u; }
  const int row = blockIdx.x * 16 + (tid >> 4);   // quarter-wave per row
  const int l16 = tid & 15;
  if (row < N_SAMP) {
    const int yi = tgt[row];
    const float4* ep = (const float4*)(E  + (size_t)row * DIM + l16 * 8);
    const float4* cp = (const float4*)(Cc + (size_t)yi  * DIM + l16 * 8);
    float4 e0 = ep[0], e1 = ep[1], c0 = cp[0], c1 = cp[1];
    float s = 0.f;
    {
      float ev[8] = {e0.x,e0.y,e0.z,e0.w,e1.x,e1.y,e1.z,e1.w};
      float cv[8] = {c0.x,c0.y,c0.z,c0.w,c1.x,c1.y,c1.z,c1.w};
      #pragma unroll
      for (int k = 0; k < 8; ++k) {
        float eh = (float)(_Float16)ev[k];
        float ch = (float)(_Float16)cv[k];
        s += ch * (ch - 2.f * eh);
      }
    }
    s += __shfl_down(s, 8, 16);
    s += __shfl_down(s, 4, 16);
    s += __shfl_down(s, 2, 16);
    s += __shfl_down(s, 1, 16);
    if (l16 == 0) rowk[row] = LAMBD + s;
  } else {
    const int cI = row - N_SAMP;
    const float4* cp = (const float4*)(Cc + (size_t)cI * DIM + l16 * 8);
    float4 c0 = cp[0], c1 = cp[1];
    float cv[8] = {c0.x,c0.y,c0.z,c0.w,c1.x,c1.y,c1.z,c1.w};
    float s = 0.f;
    #pragma unroll
    for (int k = 0; k < 8; ++k) {
      float ch = (float)(_Float16)cv[k];
      s += ch * ch;
    }
    s += __shfl_down(s, 8, 16);
    s += __shfl_down(s, 4, 16);
    s += __shfl_down(s, 2, 16);
    s += __shfl_down(s, 1, 16);
    if (l16 == 0) c2[cI] = s;
  }
}

// ---------------------------------------------------------------------------
// Main GEMM: 128x128 tile, 256 threads (4 waves 2x2), K=128 one-shot.
// Reads f32 E/C DIRECTLY from d_in (no ws round-trip), converts to f16 in
// registers, stores to LDS with the proven XOR-chunk swizzle (readers
// identical to rounds 2-6: 0 read conflicts). Epilogue has no y-mask:
// v = (rowk[row]-c2[col]) + 2*acc; sum += max(v,0); cnt += (v>0); the
// diagonal (v = lambd > 0, always counted) is subtracted in finalize.
// Bucketed slot atomics. 65 KB LDS -> 2 blocks/CU.
// ---------------------------------------------------------------------------
__global__ __launch_bounds__(256, 2) void center_gemm_kernel(
    const float* __restrict__ E, const float* __restrict__ Cc,
    const float* __restrict__ c2, const float* __restrict__ rowk,
    Slot* __restrict__ slots) {
  __shared__ _Float16 As[128 * DIM];   // 32 KB
  __shared__ _Float16 Bs[128 * DIM];   // 32 KB
  __shared__ float rowkS[128];
  __shared__ float c2S[128];
  __shared__ float swsum[4];
  __shared__ int   swcnt[4];

  const int tid  = threadIdx.x;
  const int w    = tid >> 6;
  const int lane = tid & 63;
  const int q = lane >> 4, r = lane & 15;

  const int bid = blockIdx.x;          // 0..4095
  const int bn  = bid & 31;            // col tile; consecutive bids share bm
  const int bm  = bid >> 5;            // row tile

  // ---- stage: f32 -> f16 -> LDS (XOR-swizzled chunk slots) ----
  {
    const int sr = tid >> 1;           // staged row 0..127
    const int h  = tid & 1;            // which half of the row
    const int sw = (sr & 15);
    const float4* srcA = (const float4*)(E  + (size_t)(bm * 128 + sr) * DIM + h * 64);
    const float4* srcB = (const float4*)(Cc + (size_t)(bn * 128 + sr) * DIM + h * 64);
    _Float16* dstA = As + sr * DIM;
    _Float16* dstB = Bs + sr * DIM;
    #pragma unroll
    for (int k = 0; k < 8; ++k) {
      float4 a0 = srcA[k * 2], a1 = srcA[k * 2 + 1];
      half8 ha;
      ha[0]=(_Float16)a0.x; ha[1]=(_Float16)a0.y; ha[2]=(_Float16)a0.z; ha[3]=(_Float16)a0.w;
      ha[4]=(_Float16)a1.x; ha[5]=(_Float16)a1.y; ha[6]=(_Float16)a1.z; ha[7]=(_Float16)a1.w;
      *(half8*)(dstA + (((h * 8 + k) ^ sw) * 8)) = ha;
      float4 b0 = srcB[k * 2], b1 = srcB[k * 2 + 1];
      half8 hb;
      hb[0]=(_Float16)b0.x; hb[1]=(_Float16)b0.y; hb[2]=(_Float16)b0.z; hb[3]=(_Float16)b0.w;
      hb[4]=(_Float16)b1.x; hb[5]=(_Float16)b1.y; hb[6]=(_Float16)b1.z; hb[7]=(_Float16)b1.w;
      *(half8*)(dstB + (((h * 8 + k) ^ sw) * 8)) = hb;
    }
  }
  if (tid < 128) {
    rowkS[tid] = rowk[bm * 128 + tid];
    c2S[tid]   = c2[bn * 128 + tid];
  }
  __syncthreads();

  const int wm = w >> 1, wn = w & 1;
  const int row0 = wm * 64, col0 = wn * 64;

  floatx4 acc[4][4];
  #pragma unroll
  for (int a = 0; a < 4; ++a)
    #pragma unroll
    for (int b = 0; b < 4; ++b)
      acc[a][b] = (floatx4){0.f, 0.f, 0.f, 0.f};

  #pragma unroll
  for (int ks = 0; ks < 4; ++ks) {
    const int cidx = ks * 4 + q;
    half8 af[4], bf[4];
    #pragma unroll
    for (int mt = 0; mt < 4; ++mt)
      af[mt] = *(const half8*)&As[(row0 + mt * 16 + r) * DIM + ((cidx ^ r) * 8)];
    #pragma unroll
    for (int nt = 0; nt < 4; ++nt)
      bf[nt] = *(const half8*)&Bs[(col0 + nt * 16 + r) * DIM + ((cidx ^ r) * 8)];
    #pragma unroll
    for (int mt = 0; mt < 4; ++mt)
      #pragma unroll
      for (int nt = 0; nt < 4; ++nt)
        acc[mt][nt] = __builtin_amdgcn_mfma_f32_16x16x32_f16(af[mt], bf[nt], acc[mt][nt], 0, 0, 0);
  }

  // ---- epilogue: no y-mask (diagonal corrected in finalize) ----
  float lsum = 0.f;
  int   lcnt = 0;
  #pragma unroll
  for (int mt = 0; mt < 4; ++mt) {
    float rk[4];
    #pragma unroll
    for (int rg = 0; rg < 4; ++rg)
      rk[rg] = rowkS[row0 + mt * 16 + q * 4 + rg];
    #pragma unroll
    for (int nt = 0; nt < 4; ++nt) {
      const float c2v = c2S[col0 + nt * 16 + r];
      #pragma unroll
      for (int rg = 0; rg < 4; ++rg) {
        const float v = fmaf(2.f, acc[mt][nt][rg], rk[rg] - c2v);
        lsum += fmaxf(v, 0.f);
        lcnt += (v > 0.f) ? 1 : 0;
      }
    }
  }

  #pragma unroll
  for (int off = 32; off > 0; off >>= 1) {
    lsum += __shfl_down(lsum, off);
    lcnt += __shfl_down(lcnt, off);
  }
  if (lane == 0) { swsum[w] = lsum; swcnt[w] = lcnt; }
  __syncthreads();
  if (tid == 0) {
    const float s = swsum[0] + swsum[1] + swsum[2] + swsum[3];
    const int   c = swcnt[0] + swcnt[1] + swcnt[2] + swcnt[3];
    Slot* sl = &slots[bid & (NSLOT - 1)];
    atomicAdd(&sl->sum, s);
    atomicAdd(&sl->cnt, (unsigned int)c);
  }
}

__global__ __launch_bounds__(256) void finalize_kernel(
    const Slot* __restrict__ slots, float* __restrict__ out) {
  const int tid = threadIdx.x;
  float s = slots[tid].sum;
  unsigned int c = slots[tid].cnt;
  #pragma unroll
  for (int off = 32; off > 0; off >>= 1) {
    s += __shfl_down(s, off);
    c += __shfl_down(c, off);
  }
  __shared__ float ss[4];
  __shared__ unsigned int sc[4];
  if ((tid & 63) == 0) { ss[tid >> 6] = s; sc[tid >> 6] = c; }
  __syncthreads();
  if (tid == 0) {
    // subtract the N diagonal entries (v = lambd > 0, each counted once)
    const float S = ss[0] + ss[1] + ss[2] + ss[3] - (float)N_SAMP * LAMBD;
    const float C = (float)(ss ? (sc[0] + sc[1] + sc[2] + sc[3]) : 0u) - (float)N_SAMP;
    out[0] = (C > 0.f) ? (S / C) : 0.f;
  }
}

// ---------------------------------------------------------------------------
// Fallback (tiny ws): fp32 vector path, one block per sample.
// ---------------------------------------------------------------------------
__global__ void zero_kernel(float* ws_sum, unsigned int* ws_cnt) {
  if (threadIdx.x == 0) { *ws_sum = 0.f; *ws_cnt = 0u; }
}

__global__ void finalize_simple(const float* __restrict__ ws_sum,
                                const unsigned int* __restrict__ ws_cnt,
                                float* __restrict__ out) {
  if (threadIdx.x == 0 && blockIdx.x == 0) {
    const unsigned int c = *ws_cnt;
    out[0] = (c > 0u) ? (*ws_sum / (float)c) : 0.f;
  }
}

__global__ __launch_bounds__(256) void fallback_kernel(
    const float* __restrict__ E, const float* __restrict__ Cc,
    const int* __restrict__ tgt,
    float* __restrict__ ws_sum, unsigned int* __restrict__ ws_cnt) {
  __shared__ float eS[DIM];
  __shared__ float apS;
  const int i = blockIdx.x;
  const int tid = threadIdx.x;
  if (tid < DIM) eS[tid] = E[(size_t)i * DIM + tid];
  __syncthreads();
  const int yi = tgt[i];
  float dloc[16];
  #pragma unroll
  for (int j = 0; j < 16; ++j) {
    const int c = tid + 256 * j;
    const float* cp = Cc + (size_t)c * DIM;
    float s = 0.f;
    for (int d = 0; d < DIM; d += 4) {
      float4 cv = *(const float4*)(cp + d);
      s += cv.x * (cv.x - 2.f * eS[d + 0]) + cv.y * (cv.y - 2.f * eS[d + 1])
         + cv.z * (cv.z - 2.f * eS[d + 2]) + cv.w * (cv.w - 2.f * eS[d + 3]);
    }
    dloc[j] = s;
    if (c == yi) apS = s;
  }
  __syncthreads();
  const float apv = apS;
  float lsum = 0.f; int lcnt = 0;
  #pragma unroll
  for (int j = 0; j < 16; ++j) {
    const int c = tid + 256 * j;
    const float v = LAMBD + apv - dloc[j];
    const bool mined = (v > 0.f) & (c != yi);
    lsum += mined ? v : 0.f;
    lcnt += mined ? 1 : 0;
  }
  #pragma unroll
  for (int off = 32; off > 0; off >>= 1) {
    lsum += __shfl_down(lsum, off);
    lcnt += __shfl_down(lcnt, off);
  }
  __shared__ float swsum[4];
  __shared__ int   swcnt[4];
  const int w = tid >> 6, lane = tid & 63;
  if (lane == 0) { swsum[w] = lsum; swcnt[w] = lcnt; }
  __syncthreads();
  if (tid == 0) {
    atomicAdd(ws_sum, swsum[0] + swsum[1] + swsum[2] + swsum[3]);
    atomicAdd(ws_cnt, (unsigned int)(swcnt[0] + swcnt[1] + swcnt[2] + swcnt[3]));
  }
}

extern "C" void kernel_launch(void* const* d_in, const int* in_sizes, int n_in,
                              void* d_out, int out_size, void* d_ws, size_t ws_size,
                              hipStream_t stream) {
  const float* E   = (const float*)d_in[0];
  const int*   tgt = (const int*)d_in[1];
  const float* Cc  = (const float*)d_in[2];
  float* out = (float*)d_out;

  const size_t C2_BYTES = (size_t)N_CENT * 4;           // 16 KB
  const size_t RK_BYTES = (size_t)N_SAMP * 4;           // 64 KB
  const size_t SL_BYTES = (size_t)NSLOT * sizeof(Slot); // 32 KB
  const size_t NEEDED = C2_BYTES + RK_BYTES + SL_BYTES;

  char* ws = (char*)d_ws;
  if (ws_size >= NEEDED) {
    float* c2   = (float*)ws;
    float* rowk = (float*)(ws + C2_BYTES);
    Slot* slots = (Slot*)(ws + C2_BYTES + RK_BYTES);

    prep_kernel<<<(N_SAMP + N_CENT) / 16, 256, 0, stream>>>(
        E, Cc, tgt, c2, rowk, slots);
    center_gemm_kernel<<<(N_CENT / 128) * (N_SAMP / 128), 256, 0, stream>>>(
        E, Cc, c2, rowk, slots);
    finalize_kernel<<<1, 256, 0, stream>>>(slots, out);
  } else {
    float* ws_sum = (float*)ws;
    unsigned int* ws_cnt = (unsigned int*)(ws_sum + 1);
    zero_kernel<<<1, 64, 0, stream>>>(ws_sum, ws_cnt);
    fallback_kernel<<<N_SAMP, 256, 0, stream>>>(E, Cc, tgt, ws_sum, ws_cnt);
    finalize_simple<<<1, 64, 0, stream>>>(ws_sum, ws_cnt, out);
  }
}

// Round 9
// 101.804 us; speedup vs baseline: 1.3021x; 1.3021x over previous
//
#include <hip/hip_runtime.h>

#define N_SAMP 16384
#define N_CENT 4096
#define DIM    128
#define LAMBD  1.0f
#define NSLOT  256

typedef _Float16 half8  __attribute__((ext_vector_type(8)));
typedef float    floatx4 __attribute__((ext_vector_type(4)));

struct Slot { float sum; unsigned int cnt; unsigned int pad[30]; };

// ---------------------------------------------------------------------------
// Fused prep (single launch):
//   blocks [0, 1280): quarter-wave per row; f16-ROUNDED stats so the GEMM
//     diagonal v[i,y_i] = lambd exactly (enables mask-free epilogue):
//     rows [0, N_SAMP):           rowk[i] = lambd + sum ch*(ch-2eh)
//     rows [N_SAMP, +N_CENT):     c2[c]   = sum ch*ch
//     Block 0 zeroes the 256 slots.
//   blocks [1280, 2560): f32->f16 convert of E then C (16B->8B per thread).
// ---------------------------------------------------------------------------
__global__ __launch_bounds__(256) void prep_kernel(
    const float* __restrict__ E, const float* __restrict__ Cc,
    const int* __restrict__ tgt,
    _Float16* __restrict__ Eh, _Float16* __restrict__ Ch,
    float* __restrict__ c2, float* __restrict__ rowk,
    Slot* __restrict__ slots) {
  const int tid = threadIdx.x;
  const int STAT_BLOCKS = (N_SAMP + N_CENT) / 16;  // 1280
  if ((int)blockIdx.x < STAT_BLOCKS) {
    if (blockIdx.x == 0) { slots[tid].sum = 0.f; slots[tid].cnt = 0u; }
    const int row = blockIdx.x * 16 + (tid >> 4);
    const int l16 = tid & 15;
    if (row < N_SAMP) {
      const int yi = tgt[row];
      const float4* ep = (const float4*)(E  + (size_t)row * DIM + l16 * 8);
      const float4* cp = (const float4*)(Cc + (size_t)yi  * DIM + l16 * 8);
      float4 e0 = ep[0], e1 = ep[1], c0 = cp[0], c1 = cp[1];
      float ev[8] = {e0.x,e0.y,e0.z,e0.w,e1.x,e1.y,e1.z,e1.w};
      float cv[8] = {c0.x,c0.y,c0.z,c0.w,c1.x,c1.y,c1.z,c1.w};
      float s = 0.f;
      #pragma unroll
      for (int k = 0; k < 8; ++k) {
        float eh = (float)(_Float16)ev[k];
        float ch = (float)(_Float16)cv[k];
        s += ch * (ch - 2.f * eh);
      }
      s += __shfl_down(s, 8, 16);
      s += __shfl_down(s, 4, 16);
      s += __shfl_down(s, 2, 16);
      s += __shfl_down(s, 1, 16);
      if (l16 == 0) rowk[row] = LAMBD + s;
    } else {
      const int cI = row - N_SAMP;
      const float4* cp = (const float4*)(Cc + (size_t)cI * DIM + l16 * 8);
      float4 c0 = cp[0], c1 = cp[1];
      float cv[8] = {c0.x,c0.y,c0.z,c0.w,c1.x,c1.y,c1.z,c1.w};
      float s = 0.f;
      #pragma unroll
      for (int k = 0; k < 8; ++k) {
        float ch = (float)(_Float16)cv[k];
        s += ch * ch;
      }
      s += __shfl_down(s, 8, 16);
      s += __shfl_down(s, 4, 16);
      s += __shfl_down(s, 2, 16);
      s += __shfl_down(s, 1, 16);
      if (l16 == 0) c2[cI] = s;
    }
  } else {
    const int t = ((int)blockIdx.x - STAT_BLOCKS) * 256 + tid;
    const int NE8 = N_SAMP * DIM / 8;
    const float4* src;
    half8* dst;
    int idx;
    if (t < NE8) { src = (const float4*)E;  dst = (half8*)Eh; idx = t; }
    else         { src = (const float4*)Cc; dst = (half8*)Ch; idx = t - NE8; }
    float4 a = src[(size_t)idx * 2], b = src[(size_t)idx * 2 + 1];
    half8 h;
    h[0]=(_Float16)a.x; h[1]=(_Float16)a.y; h[2]=(_Float16)a.z; h[3]=(_Float16)a.w;
    h[4]=(_Float16)b.x; h[5]=(_Float16)b.y; h[6]=(_Float16)b.z; h[7]=(_Float16)b.w;
    dst[idx] = h;
  }
}

// ---------------------------------------------------------------------------
// Main GEMM: 512 blocks (2/CU), block = 256 cols x 512 rows, 256 threads.
// Wave w owns 64 cols: B-fragments (64 cols x K=128) loaded ONCE into 64
// VGPRs and reused across a barrier-free M-loop of 8 chunks (64 rows each):
//   load af[4][4] (16 x 16B, L1-shared across waves) -> 64 MFMAs -> epilogue.
// No matrix LDS (3 KB rowk/c2 only, one barrier). Mask-free epilogue: count
// all v>0, diagonal (v=lambd) subtracted in finalize. Bucketed slot atomics.
// Staged bytes ~100 MB vs round 3's 256 MB (time model: bytes / ~7 TB/s).
// ---------------------------------------------------------------------------
__global__ __launch_bounds__(256, 2) void center_gemm_kernel(
    const _Float16* __restrict__ Eh, const _Float16* __restrict__ Ch,
    const float* __restrict__ c2, const float* __restrict__ rowk,
    Slot* __restrict__ slots) {
  __shared__ float rowkS[512];
  __shared__ float c2S[256];
  __shared__ float swsum[4];
  __shared__ int   swcnt[4];

  const int tid  = threadIdx.x;
  const int w    = tid >> 6;           // 0..3
  const int lane = tid & 63;
  const int q = lane >> 4, r = lane & 15;

  const int bid = blockIdx.x;          // 0..511
  const int cb  = bid & 15;            // 256-col tile
  const int rg  = bid >> 4;            // 512-row group

  // ---- stage rowk (512 rows) + c2 (256 cols) into LDS; one barrier ----
  rowkS[tid]       = rowk[rg * 512 + tid];
  rowkS[tid + 256] = rowk[rg * 512 + 256 + tid];
  c2S[tid]         = c2[cb * 256 + tid];
  __syncthreads();

  // ---- B-fragments: 64 cols x K=128, loaded once, register-resident ----
  const int colbase = cb * 256 + w * 64;
  half8 bf[4][4];                      // [ks][nt] : 64 VGPR
  #pragma unroll
  for (int ks = 0; ks < 4; ++ks)
    #pragma unroll
    for (int nt = 0; nt < 4; ++nt)
      bf[ks][nt] = *(const half8*)&Ch[(size_t)(colbase + nt * 16 + r) * DIM + ks * 32 + q * 8];

  // per-lane c2 for this wave's 64 cols
  float c2v[4];
  #pragma unroll
  for (int nt = 0; nt < 4; ++nt)
    c2v[nt] = c2S[w * 64 + nt * 16 + r];

  float lsum = 0.f;
  int   lcnt = 0;

  for (int c = 0; c < 8; ++c) {        // 8 chunks x 64 rows
    const int rowbase = rg * 512 + c * 64;

    half8 af[4][4];                    // [ks][mt]
    #pragma unroll
    for (int ks = 0; ks < 4; ++ks)
      #pragma unroll
      for (int mt = 0; mt < 4; ++mt)
        af[ks][mt] = *(const half8*)&Eh[(size_t)(rowbase + mt * 16 + r) * DIM + ks * 32 + q * 8];

    floatx4 acc[4][4];
    #pragma unroll
    for (int a = 0; a < 4; ++a)
      #pragma unroll
      for (int b = 0; b < 4; ++b)
        acc[a][b] = (floatx4){0.f, 0.f, 0.f, 0.f};

    #pragma unroll
    for (int ks = 0; ks < 4; ++ks)
      #pragma unroll
      for (int mt = 0; mt < 4; ++mt)
        #pragma unroll
        for (int nt = 0; nt < 4; ++nt)
          acc[mt][nt] = __builtin_amdgcn_mfma_f32_16x16x32_f16(af[ks][mt], bf[ks][nt], acc[mt][nt], 0, 0, 0);

    // ---- mask-free epilogue (diagonal corrected in finalize) ----
    const int rloc = c * 64;
    #pragma unroll
    for (int mt = 0; mt < 4; ++mt) {
      float rk[4];
      #pragma unroll
      for (int rgi = 0; rgi < 4; ++rgi)
        rk[rgi] = rowkS[rloc + mt * 16 + q * 4 + rgi];
      #pragma unroll
      for (int nt = 0; nt < 4; ++nt) {
        #pragma unroll
        for (int rgi = 0; rgi < 4; ++rgi) {
          const float v = fmaf(2.f, acc[mt][nt][rgi], rk[rgi] - c2v[nt]);
          lsum += fmaxf(v, 0.f);
          lcnt += (v > 0.f) ? 1 : 0;
        }
      }
    }
  }

  #pragma unroll
  for (int off = 32; off > 0; off >>= 1) {
    lsum += __shfl_down(lsum, off);
    lcnt += __shfl_down(lcnt, off);
  }
  if (lane == 0) { swsum[w] = lsum; swcnt[w] = lcnt; }
  __syncthreads();
  if (tid == 0) {
    const float s = swsum[0] + swsum[1] + swsum[2] + swsum[3];
    const int   c = swcnt[0] + swcnt[1] + swcnt[2] + swcnt[3];
    Slot* sl = &slots[bid & (NSLOT - 1)];
    atomicAdd(&sl->sum, s);
    atomicAdd(&sl->cnt, (unsigned int)c);
  }
}

__global__ __launch_bounds__(256) void finalize_kernel(
    const Slot* __restrict__ slots, float* __restrict__ out) {
  const int tid = threadIdx.x;
  float s = slots[tid].sum;
  unsigned int c = slots[tid].cnt;
  #pragma unroll
  for (int off = 32; off > 0; off >>= 1) {
    s += __shfl_down(s, off);
    c += __shfl_down(c, off);
  }
  __shared__ float ss[4];
  __shared__ unsigned int sc[4];
  if ((tid & 63) == 0) { ss[tid >> 6] = s; sc[tid >> 6] = c; }
  __syncthreads();
  if (tid == 0) {
    // subtract the N diagonal entries (each v = lambd > 0, counted once)
    const float S = ss[0] + ss[1] + ss[2] + ss[3] - (float)N_SAMP * LAMBD;
    const float C = (float)(sc[0] + sc[1] + sc[2] + sc[3]) - (float)N_SAMP;
    out[0] = (C > 0.f) ? (S / C) : 0.f;
  }
}

// ---------------------------------------------------------------------------
// Fallback (tiny ws): fp32 vector path, one block per sample.
// ---------------------------------------------------------------------------
__global__ void zero_kernel(float* ws_sum, unsigned int* ws_cnt) {
  if (threadIdx.x == 0) { *ws_sum = 0.f; *ws_cnt = 0u; }
}

__global__ void finalize_simple(const float* __restrict__ ws_sum,
                                const unsigned int* __restrict__ ws_cnt,
                                float* __restrict__ out) {
  if (threadIdx.x == 0 && blockIdx.x == 0) {
    const unsigned int c = *ws_cnt;
    out[0] = (c > 0u) ? (*ws_sum / (float)c) : 0.f;
  }
}

__global__ __launch_bounds__(256) void fallback_kernel(
    const float* __restrict__ E, const float* __restrict__ Cc,
    const int* __restrict__ tgt,
    float* __restrict__ ws_sum, unsigned int* __restrict__ ws_cnt) {
  __shared__ float eS[DIM];
  __shared__ float apS;
  const int i = blockIdx.x;
  const int tid = threadIdx.x;
  if (tid < DIM) eS[tid] = E[(size_t)i * DIM + tid];
  __syncthreads();
  const int yi = tgt[i];
  float dloc[16];
  #pragma unroll
  for (int j = 0; j < 16; ++j) {
    const int c = tid + 256 * j;
    const float* cp = Cc + (size_t)c * DIM;
    float s = 0.f;
    for (int d = 0; d < DIM; d += 4) {
      float4 cv = *(const float4*)(cp + d);
      s += cv.x * (cv.x - 2.f * eS[d + 0]) + cv.y * (cv.y - 2.f * eS[d + 1])
         + cv.z * (cv.z - 2.f * eS[d + 2]) + cv.w * (cv.w - 2.f * eS[d + 3]);
    }
    dloc[j] = s;
    if (c == yi) apS = s;
  }
  __syncthreads();
  const float apv = apS;
  float lsum = 0.f; int lcnt = 0;
  #pragma unroll
  for (int j = 0; j < 16; ++j) {
    const int c = tid + 256 * j;
    const float v = LAMBD + apv - dloc[j];
    const bool mined = (v > 0.f) & (c != yi);
    lsum += mined ? v : 0.f;
    lcnt += mined ? 1 : 0;
  }
  #pragma unroll
  for (int off = 32; off > 0; off >>= 1) {
    lsum += __shfl_down(lsum, off);
    lcnt += __shfl_down(lcnt, off);
  }
  __shared__ float swsum[4];
  __shared__ int   swcnt[4];
  const int w = tid >> 6, lane = tid & 63;
  if (lane == 0) { swsum[w] = lsum; swcnt[w] = lcnt; }
  __syncthreads();
  if (tid == 0) {
    atomicAdd(ws_sum, swsum[0] + swsum[1] + swsum[2] + swsum[3]);
    atomicAdd(ws_cnt, (unsigned int)(swcnt[0] + swcnt[1] + swcnt[2] + swcnt[3]));
  }
}

extern "C" void kernel_launch(void* const* d_in, const int* in_sizes, int n_in,
                              void* d_out, int out_size, void* d_ws, size_t ws_size,
                              hipStream_t stream) {
  const float* E   = (const float*)d_in[0];
  const int*   tgt = (const int*)d_in[1];
  const float* Cc  = (const float*)d_in[2];
  float* out = (float*)d_out;

  const size_t EH_BYTES = (size_t)N_SAMP * DIM * 2;     // 4 MB
  const size_t CH_BYTES = (size_t)N_CENT * DIM * 2;     // 1 MB
  const size_t C2_BYTES = (size_t)N_CENT * 4;           // 16 KB
  const size_t RK_BYTES = (size_t)N_SAMP * 4;           // 64 KB
  const size_t SL_BYTES = (size_t)NSLOT * sizeof(Slot); // 32 KB
  const size_t NEEDED = EH_BYTES + CH_BYTES + C2_BYTES + RK_BYTES + SL_BYTES;

  char* ws = (char*)d_ws;
  if (ws_size >= NEEDED) {
    _Float16* Eh = (_Float16*)ws;
    _Float16* Ch = (_Float16*)(ws + EH_BYTES);
    float* c2    = (float*)(ws + EH_BYTES + CH_BYTES);
    float* rowk  = (float*)(ws + EH_BYTES + CH_BYTES + C2_BYTES);
    Slot* slots  = (Slot*)(ws + EH_BYTES + CH_BYTES + C2_BYTES + RK_BYTES);

    const int STAT_BLOCKS = (N_SAMP + N_CENT) / 16;                       // 1280
    const int CONV_BLOCKS = (N_SAMP * DIM / 8 + N_CENT * DIM / 8) / 256;  // 1280
    prep_kernel<<<STAT_BLOCKS + CONV_BLOCKS, 256, 0, stream>>>(
        E, Cc, tgt, Eh, Ch, c2, rowk, slots);
    center_gemm_kernel<<<(N_CENT / 256) * (N_SAMP / 512), 256, 0, stream>>>(
        Eh, Ch, c2, rowk, slots);
    finalize_kernel<<<1, 256, 0, stream>>>(slots, out);
  } else {
    float* ws_sum = (float*)ws;
    unsigned int* ws_cnt = (unsigned int*)(ws_sum + 1);
    zero_kernel<<<1, 64, 0, stream>>>(ws_sum, ws_cnt);
    fallback_kernel<<<N_SAMP, 256, 0, stream>>>(E, Cc, tgt, ws_sum, ws_cnt);
    finalize_simple<<<1, 64, 0, stream>>>(ws_sum, ws_cnt, out);
  }
}